// Round 9
// baseline (2284.267 us; speedup 1.0000x reference)
//
#include <hip/hip_runtime.h>
#include <stdint.h>

typedef __attribute__((ext_vector_type(8))) short short8;
typedef __attribute__((ext_vector_type(4))) float f32x4;

#define B_N   512
#define NPIX  196
#define MTOT  (B_N*NPIX)     // 100352
#define NPAD  224            // padded pixel dim for adjacency GEMMs

static_assert(MTOT % 128 == 0, "M must tile by 128");

__device__ __forceinline__ float bf2f(unsigned short u){
  unsigned int x = ((unsigned int)u) << 16;
  return __builtin_bit_cast(float, x);
}
__device__ __forceinline__ unsigned short f2bf(float f){
  unsigned int x = __builtin_bit_cast(unsigned int, f);
  x += 0x7fffu + ((x >> 16) & 1u);          // RNE
  return (unsigned short)(x >> 16);
}
__device__ __forceinline__ void gload16(const void* g, void* l){
  __builtin_amdgcn_global_load_lds(
    (const __attribute__((address_space(1))) void*)(uintptr_t)g,
    (__attribute__((address_space(3))) void*)(uintptr_t)l, 16, 0, 0);
}
__device__ __forceinline__ float gelu_exact(float x){
  return 0.5f * x * (1.f + erff(x * 0.70710678118654752440f));
}

// ---------------------------------------------------------------------------
// 3x3 conv as implicit-im2col GEMM (round-8 structure, unchanged).
// Block tile 128x256, 512 threads = 8 waves (2M x 4N), wave tile 64x64.
// A: 160-row LDS halo via global_load_lds, dbuf per chunk; B: direct
// global->VGPR packed fragments. Zero-row address-select. 2-way swizzle.
// ---------------------------------------------------------------------------
template<int EPI>
__global__ __launch_bounds__(512, 4) void gemm_conv(
    const unsigned short* __restrict__ A, const unsigned short* __restrict__ Bt,
    unsigned short* __restrict__ outb, float* __restrict__ outf,
    const float* __restrict__ bias)
{
  __shared__ __align__(16) char smem[2*10240 + 64];   // A halo dbuf + zero row
  const int tid = threadIdx.x;
  const int wid = tid >> 6, lane = tid & 63;
  const int wr = wid >> 2, wn = wid & 3;              // 2M x 4N wave grid
  // XCD-chunked swizzle: 784 = 8 * 98 exactly
  const int orig = blockIdx.x;
  const int vid = (orig & 7) * 98 + (orig >> 3);
  const int m0 = vid * 128;

  const int ssw = ((lane & 3) ^ ((lane >> 3) & 3)) << 4;  // stage-source slot
  const int s16 = (lane >> 4) << 4;                       // logical 16B slot

  if (tid < 16) ((int*)(smem + 20480))[tid] = 0;          // zero row

  auto stageA = [&](int cc, char* dst){
#pragma unroll
    for (int s = 0; s < 2; ++s) {
      const int g = wid + s*8;
      if (g < 10) {
        const int r = g*16 + (lane >> 2);
        long gr = (long)m0 - 16 + r;
        if (gr < 0) gr = 0;
        if (gr >= MTOT) gr = MTOT - 1;
        gload16((const char*)A + (size_t)gr*512 + (size_t)cc*64 + (size_t)ssw,
                dst + g*1024);
      }
    }
  };

  f32x4 acc[4][4];
#pragma unroll
  for (int i=0;i<4;i++)
#pragma unroll
    for (int j=0;j<4;j++) acc[i][j] = (f32x4){0.f,0.f,0.f,0.f};

  int arow[4]; unsigned hh[4], ww[4];
#pragma unroll
  for (int i=0;i<4;i++){
    const int ml = wr*64 + i*16 + (lane&15);
    arow[i] = ml + 16;                       // LDS halo row for doff=0
    const int p = (m0 + ml) % NPIX;
    hh[i] = (unsigned)(p / 14); ww[i] = (unsigned)(p % 14);
  }

  // B fragment base: packed layout [tap][c][n16][kchunk][nl][ke]
  const unsigned short* bbase = Bt + ((size_t)(wn*4)*64 + lane)*8;
  const char* pz = smem + 20480 + s16;       // zero-row base

  stageA(0, smem);
  __syncthreads();

#pragma unroll 1
  for (int c = 0; c < 8; ++c) {
    if (c < 7) stageA(c+1, smem + ((c+1)&1)*10240);
    const char* aB = smem + (c&1)*10240;
#pragma unroll 3
    for (int tap = 0; tap < 9; ++tap) {
      const unsigned short* bp = bbase + (size_t)(tap*8 + c)*8192;
      short8 bv[4];
#pragma unroll
      for (int j=0;j<4;j++) bv[j] = *(const short8*)(bp + j*512);
      const int dh = tap/3 - 1, dw = tap - (tap/3)*3 - 1;
      const int doff = dh*14 + dw;
      short8 av[4];
#pragma unroll
      for (int i=0;i<4;i++){
        const int r = arow[i] + doff;
        const char* pa = aB + r*64 + (s16 ^ (((r>>1)&3)<<4));
        const bool val = (hh[i] + (unsigned)dh < 14u) && (ww[i] + (unsigned)dw < 14u);
        av[i] = *(const short8*)(val ? pa : pz);
      }
#pragma unroll
      for (int i=0;i<4;i++)
#pragma unroll
        for (int j=0;j<4;j++)
          acc[i][j] = __builtin_amdgcn_mfma_f32_16x16x32_bf16(av[i], bv[j], acc[i][j], 0,0,0);
    }
    __syncthreads();   // stageA(c+1) drain + WAR guard
  }

#pragma unroll
  for (int i=0;i<4;i++){
#pragma unroll
    for (int j=0;j<4;j++){
#pragma unroll
      for (int r=0;r<4;r++){
        const int row = m0 + wr*64 + i*16 + ((lane>>4)<<2) + r;
        const int col = wn*64 + j*16 + (lane&15);
        float v = acc[i][j][r] + bias[col];
        v = fmaxf(v, 0.f);
        outb[(size_t)row*256 + col] = f2bf(v);
        if constexpr (EPI == 1) {
          const int b = row / NPIX, p = row - b*NPIX;
          outf[((size_t)b*256 + col)*NPIX + p] = v;
        }
      }
    }
  }
}

// ---------------------------------------------------------------------------
// Fused ConvTranspose(k2,s2)+ReLU+pred(1x1)+bias.
// A fragments held ENTIRELY IN REGISTERS (64 VGPRs: areg[8][2], static idx);
// no sA -> LDS = sD only (32KB) -> 4 blocks/CU (launch_bounds 512,8).
// Per tap: dec GEMM (areg x Bdec, barrier-free) -> ReLU+bias -> bf16 sD
// (swizzled) -> barrier -> pred GEMM over K=256 -> barrier. Mask written as
// float2 (2w,2w+1) pairs after both tw taps.
// ---------------------------------------------------------------------------
__global__ __launch_bounds__(512, 8) void k_decpred(
    const unsigned short* __restrict__ A, const unsigned short* __restrict__ Bdec,
    const unsigned short* __restrict__ Bpred, const float* __restrict__ decb,
    const float* __restrict__ predb, float* __restrict__ mask)
{
  __shared__ __align__(16) char sD[32768];    // [64 rows][512B] bf16, swizzled
  const int tid = threadIdx.x;
  const int wid = tid >> 6, lane = tid & 63;
  const int m0 = blockIdx.x * 64;
  const int s16 = (lane >> 4) << 4;
  const int wr = wid >> 2, wn = wid & 3;

  // ---- A fragments -> registers (16 x short8 = 64 VGPRs) ----
  short8 areg[8][2];
#pragma unroll
  for (int c = 0; c < 8; ++c)
#pragma unroll
    for (int i = 0; i < 2; ++i) {
      const int row = m0 + wr*32 + i*16 + (lane & 15);
      areg[c][i] = *(const short8*)(A + (size_t)row*256 + c*32 + (lane>>4)*8);
    }

  float bd[4];
#pragma unroll
  for (int j = 0; j < 4; ++j) bd[j] = decb[wn*64 + j*16 + (lane & 15)];
  float pb[2]; int pcol[2];
#pragma unroll
  for (int j = 0; j < 2; ++j) {
    pcol[j] = wn*32 + j*16 + (lane & 15);
    pb[j] = (pcol[j] < 80) ? predb[pcol[j]] : 0.f;
  }

#pragma unroll 1
  for (int th = 0; th < 2; ++th) {
    f32x4 accP[2][2][2];   // [tw][i][j] -- all static indices
#pragma unroll
    for (int tw = 0; tw < 2; ++tw) {
      const int tap = th*2 + tw;
      // ---- dec GEMM: wave tile 32x64, K=256, barrier-free, A in regs ----
      f32x4 acc[2][4];
#pragma unroll
      for (int i=0;i<2;i++)
#pragma unroll
        for (int j=0;j<4;j++) acc[i][j] = (f32x4){0.f,0.f,0.f,0.f};
#pragma unroll
      for (int c = 0; c < 8; ++c) {
        short8 bv[4];
#pragma unroll
        for (int j=0;j<4;j++)
          bv[j] = *(const short8*)(Bdec + (size_t)((tap*8+c)*16 + wn*4+j)*512 + lane*8);
#pragma unroll
        for (int i=0;i<2;i++)
#pragma unroll
          for (int j=0;j<4;j++)
            acc[i][j] = __builtin_amdgcn_mfma_f32_16x16x32_bf16(areg[c][i], bv[j], acc[i][j],0,0,0);
      }
      // ---- ReLU+bias -> sD (all 8 waves, disjoint 32x64 tiles) ----
#pragma unroll
      for (int i=0;i<2;i++)
#pragma unroll
        for (int j=0;j<4;j++)
#pragma unroll
          for (int rr=0;rr<4;rr++){
            const int row = wr*32 + i*16 + ((lane>>4)<<2) + rr;
            const int colL = wn*64 + j*16 + (lane&15);
            const float v = fmaxf(acc[i][j][rr] + bd[j], 0.f);
            *(unsigned short*)(sD + row*512 + ((colL<<1) ^ ((row&7)<<4))) = f2bf(v);
          }
      __syncthreads();
      // ---- pred GEMM over full K=256, wave tile 32x32 ----
#pragma unroll
      for (int i=0;i<2;i++)
#pragma unroll
        for (int j=0;j<2;j++) accP[tw][i][j] = (f32x4){0.f,0.f,0.f,0.f};
#pragma unroll
      for (int c = 0; c < 8; ++c) {
        short8 bp2[2];
#pragma unroll
        for (int j=0;j<2;j++)
          bp2[j] = *(const short8*)(Bpred + (size_t)(c*8 + wn*2+j)*512 + lane*8);
        short8 ap[2];
#pragma unroll
        for (int i=0;i<2;i++){
          const int rP = wr*32 + i*16 + (lane&15);
          ap[i] = *(const short8*)(sD + rP*512 + ((c*64 + s16) ^ ((rP&7)<<4)));
        }
#pragma unroll
        for (int i=0;i<2;i++)
#pragma unroll
          for (int j=0;j<2;j++)
            accP[tw][i][j] = __builtin_amdgcn_mfma_f32_16x16x32_bf16(ap[i], bp2[j], accP[tw][i][j],0,0,0);
      }
      __syncthreads();   // before next tap overwrites sD
    }
    // ---- write mask: float2 pairs (2w, 2w+1) ----
#pragma unroll
    for (int i=0;i<2;i++)
#pragma unroll
      for (int j=0;j<2;j++){
        if (pcol[j] < 80) {
#pragma unroll
          for (int rr=0;rr<4;rr++){
            const int row = m0 + wr*32 + i*16 + ((lane>>4)<<2) + rr;
            const int b = row / NPIX, p = row - b*NPIX;
            const int hh = p/14, w2 = p - hh*14;
            float2 v2;
            v2.x = accP[0][i][j][rr] + pb[j];
            v2.y = accP[1][i][j][rr] + pb[j];
            *(float2*)&mask[(((size_t)b*80 + pcol[j])*28 + 2*hh + th)*28 + 2*w2] = v2;
          }
        }
      }
  }
}

// ---------------------------------------------------------------------------
// Global-M 1-tap GEMM (GCN xW). EPI 2: plain -> t_cm bf16 [(b*256+n)*224+p]
// ---------------------------------------------------------------------------
template<int KI, int EPI>
__global__ __launch_bounds__(256) void gemm_g(
    const unsigned short* __restrict__ A, const unsigned short* __restrict__ Bt,
    unsigned short* __restrict__ outb, float* __restrict__ outf,
    const float* __restrict__ bias, int th, int tw)
{
  __shared__ __align__(16) char smem[16384];
  char* sA = smem; char* sB = smem + 8192;
  const int tid = threadIdx.x;
  const int wid = tid >> 6, lane = tid & 63;
  const int wr = wid >> 1, wc = wid & 1;
  const int m0 = blockIdx.x * 128, n0 = blockIdx.y * 128;
  const int rs = wid*16 + (lane >> 2);
  const int ssw = ((lane & 3) ^ ((lane >> 3) & 3)) << 4;
  char* dA0 = sA + wid*1024; char* dA1 = sA + 4096 + wid*1024;
  char* dB0 = sB + wid*1024; char* dB1 = sB + 4096 + wid*1024;
  const char* pA0 = (const char*)(A + (size_t)(m0 + rs)      * (KI*32));
  const char* pA1 = (const char*)(A + (size_t)(m0 + rs + 64) * (KI*32));
  const char* pB0 = (const char*)(Bt + (size_t)(n0 + rs)      * (KI*32));
  const char* pB1 = (const char*)(Bt + (size_t)(n0 + rs + 64) * (KI*32));

  f32x4 acc[4][4];
#pragma unroll
  for (int i=0;i<4;i++)
#pragma unroll
    for (int j=0;j<4;j++) acc[i][j] = (f32x4){0.f,0.f,0.f,0.f};

  const int s16 = (lane >> 4) << 4;

#pragma unroll 1
  for (int kk = 0; kk < KI; ++kk) {
    const int ko = kk*64 + ssw;
    gload16(pA0 + ko, dA0);
    gload16(pA1 + ko, dA1);
    gload16(pB0 + ko, dB0);
    gload16(pB1 + ko, dB1);
    __syncthreads();
    short8 av[4], bv[4];
#pragma unroll
    for (int i=0;i<4;i++){
      const int ra = wr*64 + i*16 + (lane&15);
      const int rb = wc*64 + i*16 + (lane&15);
      av[i] = *(const short8*)(sA + ra*64 + (s16 ^ (((ra>>1)&3)<<4)));
      bv[i] = *(const short8*)(sB + rb*64 + (s16 ^ (((rb>>1)&3)<<4)));
    }
#pragma unroll
    for (int i=0;i<4;i++)
#pragma unroll
      for (int j=0;j<4;j++)
        acc[i][j] = __builtin_amdgcn_mfma_f32_16x16x32_bf16(av[i], bv[j], acc[i][j], 0,0,0);
    __syncthreads();
  }

#pragma unroll
  for (int i=0;i<4;i++){
#pragma unroll
    for (int j=0;j<4;j++){
#pragma unroll
      for (int r=0;r<4;r++){
        const int row = m0 + wr*64 + i*16 + ((lane>>4)<<2) + r;
        const int col = n0 + wc*64 + j*16 + (lane&15);
        float v = acc[i][j][r];
        if constexpr (EPI == 0) {
          v += bias[col];
          v = fmaxf(v, 0.f);
          outb[(size_t)row*256 + col] = f2bf(v);
        } else if constexpr (EPI == 2) {
          const int b = row / NPIX, p = row - b*NPIX;
          outb[((size_t)b*256 + col)*NPAD + p] = f2bf(v);
        }
      }
    }
  }
}

// ---------------------------------------------------------------------------
// Per-sample GEMM. EPI 4: adjacency with FUSED sym-normalization.
// EPI 5: gelu(acc + bias) -> bf16 act
// ---------------------------------------------------------------------------
template<int EPI, int KI>
__global__ __launch_bounds__(256) void gemm_s(
    const unsigned short* __restrict__ Asrc, int a_rps, int a_stride, long amax,
    const unsigned short* __restrict__ Bsrc, int b_rps, int b_stride, long bmax,
    unsigned short* __restrict__ outb, const float* __restrict__ bias)
{
  __shared__ __align__(16) char smem[16384];
  char* sA = smem; char* sB = smem + 8192;
  const int tid = threadIdx.x;
  const int wid = tid >> 6, lane = tid & 63;
  const int wr = wid >> 1, wc = wid & 1;
  const int m0 = blockIdx.x * 128, n0 = blockIdx.y * 128;
  const int b  = blockIdx.z;
  const int rs = wid*16 + (lane >> 2);
  const int ssw = ((lane & 3) ^ ((lane >> 3) & 3)) << 4;
  char* dA0 = sA + wid*1024; char* dA1 = sA + 4096 + wid*1024;
  char* dB0 = sB + wid*1024; char* dB1 = sB + 4096 + wid*1024;
  long ar0 = (long)b*a_rps + m0 + rs;       if (ar0 > amax) ar0 = amax;
  long ar1 = (long)b*a_rps + m0 + rs + 64;  if (ar1 > amax) ar1 = amax;
  long br0 = (long)b*b_rps + n0 + rs;       if (br0 > bmax) br0 = bmax;
  long br1 = (long)b*b_rps + n0 + rs + 64;  if (br1 > bmax) br1 = bmax;
  const char* pA0  = (const char*)(Asrc + ar0 * a_stride);
  const char* pA1  = (const char*)(Asrc + ar1 * a_stride);
  const char* pBt0 = (const char*)(Bsrc + br0 * b_stride);
  const char* pBt1 = (const char*)(Bsrc + br1 * b_stride);

  f32x4 acc[4][4];
#pragma unroll
  for (int i=0;i<4;i++)
#pragma unroll
    for (int j=0;j<4;j++) acc[i][j] = (f32x4){0.f,0.f,0.f,0.f};

  const int s16 = (lane >> 4) << 4;

#pragma unroll 1
  for (int kk = 0; kk < KI; ++kk) {
    const int ko = kk*64 + ssw;
    gload16(pA0 + ko, dA0);
    gload16(pA1 + ko, dA1);
    gload16(pBt0 + ko, dB0);
    gload16(pBt1 + ko, dB1);
    __syncthreads();
    short8 av[4], bv[4];
#pragma unroll
    for (int i=0;i<4;i++){
      const int ra = wr*64 + i*16 + (lane&15);
      const int rb = wc*64 + i*16 + (lane&15);
      av[i] = *(const short8*)(sA + ra*64 + (s16 ^ (((ra>>1)&3)<<4)));
      bv[i] = *(const short8*)(sB + rb*64 + (s16 ^ (((rb>>1)&3)<<4)));
    }
#pragma unroll
    for (int i=0;i<4;i++)
#pragma unroll
      for (int j=0;j<4;j++)
        acc[i][j] = __builtin_amdgcn_mfma_f32_16x16x32_bf16(av[i], bv[j], acc[i][j], 0,0,0);
    __syncthreads();
  }

  if constexpr (EPI == 4) {
    int nlv[4]; float dn[4];
#pragma unroll
    for (int j=0;j<4;j++){
      nlv[j] = n0 + wc*64 + j*16 + (lane&15);
      dn[j] = (nlv[j] < NPIX) ? bias[(size_t)b*NPIX + nlv[j]] : 0.f;
    }
#pragma unroll
    for (int i=0;i<4;i++){
#pragma unroll
      for (int r=0;r<4;r++){
        const int ml = m0 + wr*64 + i*16 + ((lane>>4)<<2) + r;
        const float dmv = (ml < NPIX) ? bias[(size_t)b*NPIX + ml] : 0.f;
        if (ml < NPAD) {
#pragma unroll
          for (int j=0;j<4;j++){
            if (nlv[j] < NPAD) {
              const float o = (acc[i][j][r] + ((ml==nlv[j]) ? 1.f : 0.f)) * dmv * dn[j];
              outb[((size_t)b*NPAD + ml)*NPAD + nlv[j]] = f2bf(o);
            }
          }
        }
      }
    }
  } else {  // EPI 5
#pragma unroll
    for (int i=0;i<4;i++){
#pragma unroll
      for (int j=0;j<4;j++){
#pragma unroll
        for (int r=0;r<4;r++){
          const int ml = m0 + wr*64 + i*16 + ((lane>>4)<<2) + r;
          const int nl = n0 + wc*64 + j*16 + (lane&15);
          if (ml < NPIX) {
            const float x = acc[i][j][r] + bias[nl];
            outb[((size_t)b*NPIX + ml)*256 + nl] = f2bf(gelu_exact(x));
          }
        }
      }
    }
  }
}

// --------------------------- small kernels --------------------------------

// NCHW fp32 -> pixel-major bf16 [B*196, 256]
__global__ void k_tin(const float* __restrict__ in, unsigned short* __restrict__ out)
{
  __shared__ float t[32][29];
  const int b = blockIdx.x, p0 = blockIdx.y * 28, c0 = blockIdx.z * 32;
  const int tid = threadIdx.x;
  for (int i = tid; i < 896; i += 256) {
    const int c = i / 28, p = i - c*28;
    t[c][p] = in[((size_t)b*256 + c0 + c)*196 + p0 + p];
  }
  __syncthreads();
  for (int i = tid; i < 896; i += 256) {
    const int p = i >> 5, c = i & 31;
    out[((size_t)b*196 + p0 + p)*256 + c0 + c] = f2bf(t[c][p]);
  }
}

// row-wise L2 normalize: fn = f / max(||f||, 1e-8), one wave per row
__global__ void k_fnnorm(const unsigned short* __restrict__ f, unsigned short* __restrict__ fn)
{
  const int row  = blockIdx.x * 4 + (threadIdx.x >> 6);
  const int lane = threadIdx.x & 63;
  const unsigned short* src = f + (size_t)row*256 + lane*4;
  const float x0 = bf2f(src[0]), x1 = bf2f(src[1]), x2 = bf2f(src[2]), x3 = bf2f(src[3]);
  float s = x0*x0 + x1*x1 + x2*x2 + x3*x3;
#pragma unroll
  for (int o = 32; o > 0; o >>= 1) s += __shfl_xor(s, o, 64);
  const float scale = 1.f / fmaxf(sqrtf(s), 1e-8f);
  unsigned short* dst = fn + (size_t)row*256 + lane*4;
  dst[0]=f2bf(x0*scale); dst[1]=f2bf(x1*scale); dst[2]=f2bf(x2*scale); dst[3]=f2bf(x3*scale);
}

// S[b][c] = sum_p fn[b][p][c]
__global__ void k_ssum(const unsigned short* __restrict__ fn, float* __restrict__ S)
{
  const int b = blockIdx.x, c = threadIdx.x;
  const unsigned short* p = fn + (size_t)b*NPIX*256 + c;
  float s = 0.f;
  for (int i = 0; i < NPIX; ++i) s += bf2f(p[(size_t)i*256]);
  S[b*256 + c] = s;
}

// dinv[row] = rsqrt(max(fn[row].S[b] + 1, 1e-12))
__global__ void k_dinv(const unsigned short* __restrict__ fn, const float* __restrict__ S,
                       float* __restrict__ dinv)
{
  const int row  = blockIdx.x * 4 + (threadIdx.x >> 6);
  const int lane = threadIdx.x & 63;
  const int b = row / NPIX;
  const unsigned short* p = fn + (size_t)row*256 + lane*4;
  const float* sp = S + b*256 + lane*4;
  float d = bf2f(p[0])*sp[0] + bf2f(p[1])*sp[1] + bf2f(p[2])*sp[2] + bf2f(p[3])*sp[3];
#pragma unroll
  for (int o = 32; o > 0; o >>= 1) d += __shfl_xor(d, o, 64);
  if (lane == 0) dinv[row] = rsqrtf(fmaxf(d + 1.f, 1e-12f));
}

// weight repack (bf16, fragment-coalesced) + t_cm K-pad zeroing
__global__ void k_prep(const float* __restrict__ cnn_w, const float* __restrict__ up_w,
                       const float* __restrict__ gcn_w, const float* __restrict__ dec_w,
                       const float* __restrict__ pred_w,
                       unsigned short* __restrict__ bt_cnn, unsigned short* __restrict__ bt_up,
                       unsigned short* __restrict__ bt_gcn, unsigned short* __restrict__ bt_dec,
                       unsigned short* __restrict__ bt_pred, unsigned short* __restrict__ tcm)
{
  long i = (long)blockIdx.x * 256 + threadIdx.x;
  long n = 4L*589824;
  if (i < n) {  // [tap][c][n16][kchunk][nl][ke]
    const long l = i / 589824, r = i % 589824;
    const long tap = r >> 16, r2 = r & 65535;
    const long c = r2 >> 13, n16 = (r2 >> 9) & 15, kchunk = (r2 >> 7) & 3;
    const long nl = (r2 >> 3) & 15, ke = r2 & 7;
    const long co = n16*16 + nl, ci = c*32 + kchunk*8 + ke;
    bt_cnn[i] = f2bf(cnn_w[(((l*256+co)*256+ci)*3 + tap/3)*3 + (tap%3)]);
    return;
  }
  i -= n; n = 2L*589824;
  if (i < n) {
    const long l = i / 589824, r = i % 589824;
    const long tap = r >> 16, r2 = r & 65535;
    const long c = r2 >> 13, n16 = (r2 >> 9) & 15, kchunk = (r2 >> 7) & 3;
    const long nl = (r2 >> 3) & 15, ke = r2 & 7;
    const long co = n16*16 + nl, ci = c*32 + kchunk*8 + ke;
    bt_up[i] = f2bf(up_w[(((l*256+co)*256+ci)*3 + tap/3)*3 + (tap%3)]);
    return;
  }
  i -= n; n = 2L*256*256;
  if (i < n) {  // Bt_gcn[l][co][ci] = gcn_w[l][ci][co]
    const long ci = i & 255, co = (i >> 8) & 255, l = i >> 16;
    bt_gcn[i] = f2bf(gcn_w[(l*256 + ci)*256 + co]);
    return;
  }
  i -= n; n = 262144;
  if (i < n) {  // dec packed [tap][c][g16][k4][nl][ke]
    const long ke = i&7, nl = (i>>3)&15, k4 = (i>>7)&3, g = (i>>9)&15;
    const long c = (i>>13)&7, tap = i>>16;
    const long co = g*16 + nl, ci = c*32 + k4*8 + ke;
    bt_dec[i] = f2bf(dec_w[((ci*256 + co)*2 + (tap>>1))*2 + (tap&1)]);
    return;
  }
  i -= n; n = 32768;
  if (i < n) {  // pred packed [c][g8][k4][nl][ke], cls>=80 -> 0
    const long ke = i&7, nl = (i>>3)&15, k4 = (i>>7)&3, g = (i>>9)&7, c = i>>12;
    const long cls = g*16 + nl, ci = c*32 + k4*8 + ke;
    bt_pred[i] = (cls < 80) ? f2bf(pred_w[cls*256 + ci]) : (unsigned short)0;
    return;
  }
  i -= n; n = 512L*256*28;
  if (i < n) {  // t_cm[b][c][196..223] = 0
    const long p = 196 + (i % 28);
    const long rest = i / 28;
    const long c = rest & 255, bb = rest >> 8;
    tcm[((size_t)(bb*256 + c))*NPAD + p] = 0;
    return;
  }
}

// ---------------------------------------------------------------------------
extern "C" void kernel_launch(void* const* d_in, const int* in_sizes, int n_in,
                              void* d_out, int out_size, void* d_ws, size_t ws_size,
                              hipStream_t stream)
{
  const float* features = (const float*)d_in[0];
  const float* cnn_w  = (const float*)d_in[1];
  const float* cnn_b  = (const float*)d_in[2];
  const float* gcn_w  = (const float*)d_in[3];
  const float* gcn_b  = (const float*)d_in[4];
  const float* up_w   = (const float*)d_in[5];
  const float* up_b   = (const float*)d_in[6];
  const float* dec_w  = (const float*)d_in[7];
  const float* dec_b  = (const float*)d_in[8];
  const float* pred_w = (const float*)d_in[9];
  const float* pred_b = (const float*)d_in[10];

  char* ws = (char*)d_ws;
  size_t o = 0;
  auto take = [&](size_t nbytes) -> char* {
    char* p = ws + o;
    o += (nbytes + 255) & ~(size_t)255;
    return p;
  };
  unsigned short* bt_cnn  = (unsigned short*)take(4L*589824*2);
  unsigned short* bt_up   = (unsigned short*)take(2L*589824*2);
  unsigned short* bt_gcn  = (unsigned short*)take(2L*256*256*2);
  unsigned short* bt_dec  = (unsigned short*)take(262144L*2);
  unsigned short* bt_pred = (unsigned short*)take(32768L*2);
  unsigned short* actA    = (unsigned short*)take((size_t)MTOT*256*2);
  unsigned short* actB    = (unsigned short*)take((size_t)MTOT*256*2);
  unsigned short* ahat    = (unsigned short*)take((size_t)B_N*NPAD*NPAD*2);
  unsigned short* tcm     = (unsigned short*)take((size_t)B_N*256*NPAD*2);
  float*          Sbuf    = (float*)take((size_t)B_N*256*4);
  float*          dinvb   = (float*)take((size_t)MTOT*4);

  float* mask  = (float*)d_out;
  float* feats = mask + (size_t)B_N*80*28*28;

  const dim3 blk(256);
  const dim3 gc(784);                // conv: 1-D, XCD-swizzled in-kernel
  const dim3 gg(MTOT/128, 2);        // 784 x 2
  const dim3 gs(2, 2, B_N);

  k_prep<<<29824, blk, 0, stream>>>(cnn_w, up_w, gcn_w, dec_w, pred_w,
                                    bt_cnn, bt_up, bt_gcn, bt_dec, bt_pred, tcm);
  k_tin<<<dim3(B_N, 7, 8), blk, 0, stream>>>(features, actA);

  // CNN stack (4x conv3x3+relu), ping-pong actA/actB
  gemm_conv<0><<<gc, dim3(512), 0, stream>>>(actA, bt_cnn + 0L*589824, actB, nullptr, cnn_b + 0);
  gemm_conv<0><<<gc, dim3(512), 0, stream>>>(actB, bt_cnn + 1L*589824, actA, nullptr, cnn_b + 256);
  gemm_conv<0><<<gc, dim3(512), 0, stream>>>(actA, bt_cnn + 2L*589824, actB, nullptr, cnn_b + 512);
  gemm_conv<0><<<gc, dim3(512), 0, stream>>>(actB, bt_cnn + 3L*589824, actA, nullptr, cnn_b + 768);
  // f = actA

  // cosine adjacency with fused normalization
  k_fnnorm<<<MTOT/4, blk, 0, stream>>>(actA, actB);     // fn = actB
  k_ssum<<<B_N, blk, 0, stream>>>(actB, Sbuf);
  k_dinv<<<MTOT/4, blk, 0, stream>>>(actB, Sbuf, dinvb);
  gemm_s<4,8><<<gs, blk, 0, stream>>>(actB, NPIX, 256, (long)MTOT-1,
                                      actB, NPIX, 256, (long)MTOT-1, ahat, dinvb);

  // GCN layer 1: t = g @ W1 (channel-major), g1 = gelu(A_hat @ t + b1)
  gemm_g<8,2><<<gg, blk, 0, stream>>>(actA, bt_gcn, tcm, nullptr, nullptr, 0,0);
  gemm_s<5,7><<<gs, blk, 0, stream>>>(ahat, NPAD, NPAD, (long)B_N*NPAD-1,
                                      tcm, 256, NPAD, (long)B_N*256-1, actB, gcn_b);
  // GCN layer 2
  gemm_g<8,2><<<gg, blk, 0, stream>>>(actB, bt_gcn + 65536, tcm, nullptr, nullptr, 0,0);
  gemm_s<5,7><<<gs, blk, 0, stream>>>(ahat, NPAD, NPAD, (long)B_N*NPAD-1,
                                      tcm, 256, NPAD, (long)B_N*256-1, actA, gcn_b + 256);

  // Upsample head convs; second one also writes fp32 feats (output 1)
  gemm_conv<0><<<gc, dim3(512), 0, stream>>>(actA, bt_up + 0L*589824, actB, nullptr, up_b + 0);
  gemm_conv<1><<<gc, dim3(512), 0, stream>>>(actB, bt_up + 1L*589824, actA, feats,   up_b + 256);

  // Fused ConvTranspose(k2,s2)+ReLU+pred(1x1), A in registers
  k_decpred<<<dim3(MTOT/64), dim3(512), 0, stream>>>(actA, bt_dec, bt_pred,
                                                     dec_b, pred_b, mask);
}

// Round 10
// 1709.839 us; speedup vs baseline: 1.3360x; 1.3360x over previous
//
#include <hip/hip_runtime.h>
#include <stdint.h>

typedef __attribute__((ext_vector_type(8))) short short8;
typedef __attribute__((ext_vector_type(4))) float f32x4;

#define B_N   512
#define NPIX  196
#define MTOT  (B_N*NPIX)     // 100352
#define NPAD  224            // padded pixel dim for adjacency GEMMs

static_assert(MTOT % 128 == 0, "M must tile by 128");

__device__ __forceinline__ float bf2f(unsigned short u){
  unsigned int x = ((unsigned int)u) << 16;
  return __builtin_bit_cast(float, x);
}
__device__ __forceinline__ unsigned short f2bf(float f){
  unsigned int x = __builtin_bit_cast(unsigned int, f);
  x += 0x7fffu + ((x >> 16) & 1u);          // RNE
  return (unsigned short)(x >> 16);
}
__device__ __forceinline__ void gload16(const void* g, void* l){
  __builtin_amdgcn_global_load_lds(
    (const __attribute__((address_space(1))) void*)(uintptr_t)g,
    (__attribute__((address_space(3))) void*)(uintptr_t)l, 16, 0, 0);
}
__device__ __forceinline__ float gelu_exact(float x){
  return 0.5f * x * (1.f + erff(x * 0.70710678118654752440f));
}

// ---------------------------------------------------------------------------
// 3x3 conv as implicit-im2col GEMM (round-8 structure, unchanged).
// Block tile 128x256, 512 threads = 8 waves (2M x 4N), wave tile 64x64.
// A: 160-row LDS halo via global_load_lds, dbuf per chunk; B: direct
// global->VGPR packed fragments. Zero-row address-select. 2-way swizzle.
// ---------------------------------------------------------------------------
template<int EPI>
__global__ __launch_bounds__(512, 4) void gemm_conv(
    const unsigned short* __restrict__ A, const unsigned short* __restrict__ Bt,
    unsigned short* __restrict__ outb, float* __restrict__ outf,
    const float* __restrict__ bias)
{
  __shared__ __align__(16) char smem[2*10240 + 64];   // A halo dbuf + zero row
  const int tid = threadIdx.x;
  const int wid = tid >> 6, lane = tid & 63;
  const int wr = wid >> 2, wn = wid & 3;              // 2M x 4N wave grid
  // XCD-chunked swizzle: 784 = 8 * 98 exactly
  const int orig = blockIdx.x;
  const int vid = (orig & 7) * 98 + (orig >> 3);
  const int m0 = vid * 128;

  const int ssw = ((lane & 3) ^ ((lane >> 3) & 3)) << 4;  // stage-source slot
  const int s16 = (lane >> 4) << 4;                       // logical 16B slot

  if (tid < 16) ((int*)(smem + 20480))[tid] = 0;          // zero row

  auto stageA = [&](int cc, char* dst){
#pragma unroll
    for (int s = 0; s < 2; ++s) {
      const int g = wid + s*8;
      if (g < 10) {
        const int r = g*16 + (lane >> 2);
        long gr = (long)m0 - 16 + r;
        if (gr < 0) gr = 0;
        if (gr >= MTOT) gr = MTOT - 1;
        gload16((const char*)A + (size_t)gr*512 + (size_t)cc*64 + (size_t)ssw,
                dst + g*1024);
      }
    }
  };

  f32x4 acc[4][4];
#pragma unroll
  for (int i=0;i<4;i++)
#pragma unroll
    for (int j=0;j<4;j++) acc[i][j] = (f32x4){0.f,0.f,0.f,0.f};

  int arow[4]; unsigned hh[4], ww[4];
#pragma unroll
  for (int i=0;i<4;i++){
    const int ml = wr*64 + i*16 + (lane&15);
    arow[i] = ml + 16;                       // LDS halo row for doff=0
    const int p = (m0 + ml) % NPIX;
    hh[i] = (unsigned)(p / 14); ww[i] = (unsigned)(p % 14);
  }

  // B fragment base: packed layout [tap][c][n16][kchunk][nl][ke]
  const unsigned short* bbase = Bt + ((size_t)(wn*4)*64 + lane)*8;
  const char* pz = smem + 20480 + s16;       // zero-row base

  stageA(0, smem);
  __syncthreads();

#pragma unroll 1
  for (int c = 0; c < 8; ++c) {
    if (c < 7) stageA(c+1, smem + ((c+1)&1)*10240);
    const char* aB = smem + (c&1)*10240;
#pragma unroll 3
    for (int tap = 0; tap < 9; ++tap) {
      const unsigned short* bp = bbase + (size_t)(tap*8 + c)*8192;
      short8 bv[4];
#pragma unroll
      for (int j=0;j<4;j++) bv[j] = *(const short8*)(bp + j*512);
      const int dh = tap/3 - 1, dw = tap - (tap/3)*3 - 1;
      const int doff = dh*14 + dw;
      short8 av[4];
#pragma unroll
      for (int i=0;i<4;i++){
        const int r = arow[i] + doff;
        const char* pa = aB + r*64 + (s16 ^ (((r>>1)&3)<<4));
        const bool val = (hh[i] + (unsigned)dh < 14u) && (ww[i] + (unsigned)dw < 14u);
        av[i] = *(const short8*)(val ? pa : pz);
      }
#pragma unroll
      for (int i=0;i<4;i++)
#pragma unroll
        for (int j=0;j<4;j++)
          acc[i][j] = __builtin_amdgcn_mfma_f32_16x16x32_bf16(av[i], bv[j], acc[i][j], 0,0,0);
    }
    __syncthreads();   // stageA(c+1) drain + WAR guard
  }

#pragma unroll
  for (int i=0;i<4;i++){
#pragma unroll
    for (int j=0;j<4;j++){
#pragma unroll
      for (int r=0;r<4;r++){
        const int row = m0 + wr*64 + i*16 + ((lane>>4)<<2) + r;
        const int col = wn*64 + j*16 + (lane&15);
        float v = acc[i][j][r] + bias[col];
        v = fmaxf(v, 0.f);
        outb[(size_t)row*256 + col] = f2bf(v);
        if constexpr (EPI == 1) {
          const int b = row / NPIX, p = row - b*NPIX;
          outf[((size_t)b*256 + col)*NPIX + p] = v;
        }
      }
    }
  }
}

// ---------------------------------------------------------------------------
// Fused ConvTranspose(k2,s2)+ReLU+pred(1x1)+bias. 256 threads / 4 waves,
// M-tile 32, LDS 32KB (sA 16KB + sD 16KB) -> 4 blocks/CU at VGPR<=128
// (launch_bounds 256,4). Same per-thread state as R8 (fit 128 there); no
// reg-A (R9 showed it cannot fit any multi-block VGPR budget). 4 independent
// barrier domains/CU (vs R8's 2) hide the serial dec->sD->pred chain.
// ---------------------------------------------------------------------------
__global__ __launch_bounds__(256, 4) void k_decpred(
    const unsigned short* __restrict__ A, const unsigned short* __restrict__ Bdec,
    const unsigned short* __restrict__ Bpred, const float* __restrict__ decb,
    const float* __restrict__ predb, float* __restrict__ mask)
{
  __shared__ __align__(16) char smem[32768];
  char* sA = smem;            // [8 chunks][32 rows][64B], XOR-swizzled
  char* sD = smem + 16384;    // [32 rows][512B] bf16 dec-out, swizzled
  const int tid = threadIdx.x;
  const int wid = tid >> 6, lane = tid & 63;
  const int m0 = blockIdx.x * 32;
  const int ssw = ((lane & 3) ^ ((lane >> 3) & 3)) << 4;
  const int s16 = (lane >> 4) << 4;
  const int wn = wid;                        // 4 N-position waves

  // ---- stage A tile (32 rows x 256 ch), 4 gload16/thread ----
#pragma unroll
  for (int p = 0; p < 4; ++p) {
    const int cc = p*2 + (wid >> 1);
    const int r  = (wid & 1)*16 + (lane >> 2);
    gload16((const char*)A + (size_t)(m0 + r)*512 + (size_t)cc*64 + (size_t)ssw,
            sA + cc*2048 + (wid & 1)*1024);
  }

  float bd[4];
#pragma unroll
  for (int j = 0; j < 4; ++j) bd[j] = decb[wn*64 + j*16 + (lane & 15)];
  float pb[2]; int pcol[2];
#pragma unroll
  for (int j = 0; j < 2; ++j) {
    pcol[j] = wn*32 + j*16 + (lane & 15);
    pb[j] = (pcol[j] < 80) ? predb[pcol[j]] : 0.f;
  }

  __syncthreads();

#pragma unroll 1
  for (int th = 0; th < 2; ++th) {
    f32x4 accP[2][2][2];   // [tw][i][j] -- all static indices
#pragma unroll
    for (int tw = 0; tw < 2; ++tw) {
      const int tap = th*2 + tw;
      // ---- dec GEMM: wave tile 32x64, K=256, barrier-free ----
      f32x4 acc[2][4];
#pragma unroll
      for (int i=0;i<2;i++)
#pragma unroll
        for (int j=0;j<4;j++) acc[i][j] = (f32x4){0.f,0.f,0.f,0.f};
#pragma unroll
      for (int c = 0; c < 8; ++c) {
        short8 bv[4];
#pragma unroll
        for (int j=0;j<4;j++)
          bv[j] = *(const short8*)(Bdec + (size_t)((tap*8+c)*16 + wn*4+j)*512 + lane*8);
        short8 av[2];
#pragma unroll
        for (int i=0;i<2;i++){
          const int rA = i*16 + (lane&15);
          av[i] = *(const short8*)(sA + c*2048 + rA*64 + (s16 ^ (((rA>>1)&3)<<4)));
        }
#pragma unroll
        for (int i=0;i<2;i++)
#pragma unroll
          for (int j=0;j<4;j++)
            acc[i][j] = __builtin_amdgcn_mfma_f32_16x16x32_bf16(av[i], bv[j], acc[i][j],0,0,0);
      }
      // ---- ReLU+bias -> sD (4 waves, disjoint 32-col stripes) ----
#pragma unroll
      for (int i=0;i<2;i++)
#pragma unroll
        for (int j=0;j<4;j++)
#pragma unroll
          for (int rr=0;rr<4;rr++){
            const int row = i*16 + ((lane>>4)<<2) + rr;
            const int colL = wn*64 + j*16 + (lane&15);
            const float v = fmaxf(acc[i][j][rr] + bd[j], 0.f);
            *(unsigned short*)(sD + row*512 + ((colL<<1) ^ ((row&7)<<4))) = f2bf(v);
          }
      __syncthreads();
      // ---- pred GEMM over full K=256, wave tile 32x32 ----
#pragma unroll
      for (int i=0;i<2;i++)
#pragma unroll
        for (int j=0;j<2;j++) accP[tw][i][j] = (f32x4){0.f,0.f,0.f,0.f};
#pragma unroll
      for (int c = 0; c < 8; ++c) {
        short8 bp2[2];
#pragma unroll
        for (int j=0;j<2;j++)
          bp2[j] = *(const short8*)(Bpred + (size_t)(c*8 + wn*2+j)*512 + lane*8);
        short8 ap[2];
#pragma unroll
        for (int i=0;i<2;i++){
          const int rP = i*16 + (lane&15);
          ap[i] = *(const short8*)(sD + rP*512 + ((c*64 + s16) ^ ((rP&7)<<4)));
        }
#pragma unroll
        for (int i=0;i<2;i++)
#pragma unroll
          for (int j=0;j<2;j++)
            accP[tw][i][j] = __builtin_amdgcn_mfma_f32_16x16x32_bf16(ap[i], bp2[j], accP[tw][i][j],0,0,0);
      }
      __syncthreads();   // before next tap overwrites sD
    }
    // ---- write mask: float2 pairs (2w, 2w+1) ----
#pragma unroll
    for (int i=0;i<2;i++)
#pragma unroll
      for (int j=0;j<2;j++){
        if (pcol[j] < 80) {
#pragma unroll
          for (int rr=0;rr<4;rr++){
            const int row = m0 + i*16 + ((lane>>4)<<2) + rr;
            const int b = row / NPIX, p = row - b*NPIX;
            const int hh = p/14, w2 = p - hh*14;
            float2 v2;
            v2.x = accP[0][i][j][rr] + pb[j];
            v2.y = accP[1][i][j][rr] + pb[j];
            *(float2*)&mask[(((size_t)b*80 + pcol[j])*28 + 2*hh + th)*28 + 2*w2] = v2;
          }
        }
      }
  }
}

// ---------------------------------------------------------------------------
// Global-M 1-tap GEMM (GCN xW). EPI 2: plain -> t_cm bf16 [(b*256+n)*224+p]
// ---------------------------------------------------------------------------
template<int KI, int EPI>
__global__ __launch_bounds__(256) void gemm_g(
    const unsigned short* __restrict__ A, const unsigned short* __restrict__ Bt,
    unsigned short* __restrict__ outb, float* __restrict__ outf,
    const float* __restrict__ bias, int th, int tw)
{
  __shared__ __align__(16) char smem[16384];
  char* sA = smem; char* sB = smem + 8192;
  const int tid = threadIdx.x;
  const int wid = tid >> 6, lane = tid & 63;
  const int wr = wid >> 1, wc = wid & 1;
  const int m0 = blockIdx.x * 128, n0 = blockIdx.y * 128;
  const int rs = wid*16 + (lane >> 2);
  const int ssw = ((lane & 3) ^ ((lane >> 3) & 3)) << 4;
  char* dA0 = sA + wid*1024; char* dA1 = sA + 4096 + wid*1024;
  char* dB0 = sB + wid*1024; char* dB1 = sB + 4096 + wid*1024;
  const char* pA0 = (const char*)(A + (size_t)(m0 + rs)      * (KI*32));
  const char* pA1 = (const char*)(A + (size_t)(m0 + rs + 64) * (KI*32));
  const char* pB0 = (const char*)(Bt + (size_t)(n0 + rs)      * (KI*32));
  const char* pB1 = (const char*)(Bt + (size_t)(n0 + rs + 64) * (KI*32));

  f32x4 acc[4][4];
#pragma unroll
  for (int i=0;i<4;i++)
#pragma unroll
    for (int j=0;j<4;j++) acc[i][j] = (f32x4){0.f,0.f,0.f,0.f};

  const int s16 = (lane >> 4) << 4;

#pragma unroll 1
  for (int kk = 0; kk < KI; ++kk) {
    const int ko = kk*64 + ssw;
    gload16(pA0 + ko, dA0);
    gload16(pA1 + ko, dA1);
    gload16(pB0 + ko, dB0);
    gload16(pB1 + ko, dB1);
    __syncthreads();
    short8 av[4], bv[4];
#pragma unroll
    for (int i=0;i<4;i++){
      const int ra = wr*64 + i*16 + (lane&15);
      const int rb = wc*64 + i*16 + (lane&15);
      av[i] = *(const short8*)(sA + ra*64 + (s16 ^ (((ra>>1)&3)<<4)));
      bv[i] = *(const short8*)(sB + rb*64 + (s16 ^ (((rb>>1)&3)<<4)));
    }
#pragma unroll
    for (int i=0;i<4;i++)
#pragma unroll
      for (int j=0;j<4;j++)
        acc[i][j] = __builtin_amdgcn_mfma_f32_16x16x32_bf16(av[i], bv[j], acc[i][j], 0,0,0);
    __syncthreads();
  }

#pragma unroll
  for (int i=0;i<4;i++){
#pragma unroll
    for (int j=0;j<4;j++){
#pragma unroll
      for (int r=0;r<4;r++){
        const int row = m0 + wr*64 + i*16 + ((lane>>4)<<2) + r;
        const int col = n0 + wc*64 + j*16 + (lane&15);
        float v = acc[i][j][r];
        if constexpr (EPI == 0) {
          v += bias[col];
          v = fmaxf(v, 0.f);
          outb[(size_t)row*256 + col] = f2bf(v);
        } else if constexpr (EPI == 2) {
          const int b = row / NPIX, p = row - b*NPIX;
          outb[((size_t)b*256 + col)*NPAD + p] = f2bf(v);
        }
      }
    }
  }
}

// ---------------------------------------------------------------------------
// Per-sample GEMM. EPI 4: adjacency with FUSED sym-normalization.
// EPI 5: gelu(acc + bias) -> bf16 act
// ---------------------------------------------------------------------------
template<int EPI, int KI>
__global__ __launch_bounds__(256) void gemm_s(
    const unsigned short* __restrict__ Asrc, int a_rps, int a_stride, long amax,
    const unsigned short* __restrict__ Bsrc, int b_rps, int b_stride, long bmax,
    unsigned short* __restrict__ outb, const float* __restrict__ bias)
{
  __shared__ __align__(16) char smem[16384];
  char* sA = smem; char* sB = smem + 8192;
  const int tid = threadIdx.x;
  const int wid = tid >> 6, lane = tid & 63;
  const int wr = wid >> 1, wc = wid & 1;
  const int m0 = blockIdx.x * 128, n0 = blockIdx.y * 128;
  const int b  = blockIdx.z;
  const int rs = wid*16 + (lane >> 2);
  const int ssw = ((lane & 3) ^ ((lane >> 3) & 3)) << 4;
  char* dA0 = sA + wid*1024; char* dA1 = sA + 4096 + wid*1024;
  char* dB0 = sB + wid*1024; char* dB1 = sB + 4096 + wid*1024;
  long ar0 = (long)b*a_rps + m0 + rs;       if (ar0 > amax) ar0 = amax;
  long ar1 = (long)b*a_rps + m0 + rs + 64;  if (ar1 > amax) ar1 = amax;
  long br0 = (long)b*b_rps + n0 + rs;       if (br0 > bmax) br0 = bmax;
  long br1 = (long)b*b_rps + n0 + rs + 64;  if (br1 > bmax) br1 = bmax;
  const char* pA0  = (const char*)(Asrc + ar0 * a_stride);
  const char* pA1  = (const char*)(Asrc + ar1 * a_stride);
  const char* pBt0 = (const char*)(Bsrc + br0 * b_stride);
  const char* pBt1 = (const char*)(Bsrc + br1 * b_stride);

  f32x4 acc[4][4];
#pragma unroll
  for (int i=0;i<4;i++)
#pragma unroll
    for (int j=0;j<4;j++) acc[i][j] = (f32x4){0.f,0.f,0.f,0.f};

  const int s16 = (lane >> 4) << 4;

#pragma unroll 1
  for (int kk = 0; kk < KI; ++kk) {
    const int ko = kk*64 + ssw;
    gload16(pA0 + ko, dA0);
    gload16(pA1 + ko, dA1);
    gload16(pBt0 + ko, dB0);
    gload16(pBt1 + ko, dB1);
    __syncthreads();
    short8 av[4], bv[4];
#pragma unroll
    for (int i=0;i<4;i++){
      const int ra = wr*64 + i*16 + (lane&15);
      const int rb = wc*64 + i*16 + (lane&15);
      av[i] = *(const short8*)(sA + ra*64 + (s16 ^ (((ra>>1)&3)<<4)));
      bv[i] = *(const short8*)(sB + rb*64 + (s16 ^ (((rb>>1)&3)<<4)));
    }
#pragma unroll
    for (int i=0;i<4;i++)
#pragma unroll
      for (int j=0;j<4;j++)
        acc[i][j] = __builtin_amdgcn_mfma_f32_16x16x32_bf16(av[i], bv[j], acc[i][j], 0,0,0);
    __syncthreads();
  }

  if constexpr (EPI == 4) {
    int nlv[4]; float dn[4];
#pragma unroll
    for (int j=0;j<4;j++){
      nlv[j] = n0 + wc*64 + j*16 + (lane&15);
      dn[j] = (nlv[j] < NPIX) ? bias[(size_t)b*NPIX + nlv[j]] : 0.f;
    }
#pragma unroll
    for (int i=0;i<4;i++){
#pragma unroll
      for (int r=0;r<4;r++){
        const int ml = m0 + wr*64 + i*16 + ((lane>>4)<<2) + r;
        const float dmv = (ml < NPIX) ? bias[(size_t)b*NPIX + ml] : 0.f;
        if (ml < NPAD) {
#pragma unroll
          for (int j=0;j<4;j++){
            if (nlv[j] < NPAD) {
              const float o = (acc[i][j][r] + ((ml==nlv[j]) ? 1.f : 0.f)) * dmv * dn[j];
              outb[((size_t)b*NPAD + ml)*NPAD + nlv[j]] = f2bf(o);
            }
          }
        }
      }
    }
  } else {  // EPI 5
#pragma unroll
    for (int i=0;i<4;i++){
#pragma unroll
      for (int j=0;j<4;j++){
#pragma unroll
        for (int r=0;r<4;r++){
          const int ml = m0 + wr*64 + i*16 + ((lane>>4)<<2) + r;
          const int nl = n0 + wc*64 + j*16 + (lane&15);
          if (ml < NPIX) {
            const float x = acc[i][j][r] + bias[nl];
            outb[((size_t)b*NPIX + ml)*256 + nl] = f2bf(gelu_exact(x));
          }
        }
      }
    }
  }
}

// --------------------------- small kernels --------------------------------

// NCHW fp32 -> pixel-major bf16 [B*196, 256]
__global__ void k_tin(const float* __restrict__ in, unsigned short* __restrict__ out)
{
  __shared__ float t[32][29];
  const int b = blockIdx.x, p0 = blockIdx.y * 28, c0 = blockIdx.z * 32;
  const int tid = threadIdx.x;
  for (int i = tid; i < 896; i += 256) {
    const int c = i / 28, p = i - c*28;
    t[c][p] = in[((size_t)b*256 + c0 + c)*196 + p0 + p];
  }
  __syncthreads();
  for (int i = tid; i < 896; i += 256) {
    const int p = i >> 5, c = i & 31;
    out[((size_t)b*196 + p0 + p)*256 + c0 + c] = f2bf(t[c][p]);
  }
}

// row-wise L2 normalize: fn = f / max(||f||, 1e-8), one wave per row
__global__ void k_fnnorm(const unsigned short* __restrict__ f, unsigned short* __restrict__ fn)
{
  const int row  = blockIdx.x * 4 + (threadIdx.x >> 6);
  const int lane = threadIdx.x & 63;
  const unsigned short* src = f + (size_t)row*256 + lane*4;
  const float x0 = bf2f(src[0]), x1 = bf2f(src[1]), x2 = bf2f(src[2]), x3 = bf2f(src[3]);
  float s = x0*x0 + x1*x1 + x2*x2 + x3*x3;
#pragma unroll
  for (int o = 32; o > 0; o >>= 1) s += __shfl_xor(s, o, 64);
  const float scale = 1.f / fmaxf(sqrtf(s), 1e-8f);
  unsigned short* dst = fn + (size_t)row*256 + lane*4;
  dst[0]=f2bf(x0*scale); dst[1]=f2bf(x1*scale); dst[2]=f2bf(x2*scale); dst[3]=f2bf(x3*scale);
}

// S[b][c] = sum_p fn[b][p][c]
__global__ void k_ssum(const unsigned short* __restrict__ fn, float* __restrict__ S)
{
  const int b = blockIdx.x, c = threadIdx.x;
  const unsigned short* p = fn + (size_t)b*NPIX*256 + c;
  float s = 0.f;
  for (int i = 0; i < NPIX; ++i) s += bf2f(p[(size_t)i*256]);
  S[b*256 + c] = s;
}

// dinv[row] = rsqrt(max(fn[row].S[b] + 1, 1e-12))
__global__ void k_dinv(const unsigned short* __restrict__ fn, const float* __restrict__ S,
                       float* __restrict__ dinv)
{
  const int row  = blockIdx.x * 4 + (threadIdx.x >> 6);
  const int lane = threadIdx.x & 63;
  const int b = row / NPIX;
  const unsigned short* p = fn + (size_t)row*256 + lane*4;
  const float* sp = S + b*256 + lane*4;
  float d = bf2f(p[0])*sp[0] + bf2f(p[1])*sp[1] + bf2f(p[2])*sp[2] + bf2f(p[3])*sp[3];
#pragma unroll
  for (int o = 32; o > 0; o >>= 1) d += __shfl_xor(d, o, 64);
  if (lane == 0) dinv[row] = rsqrtf(fmaxf(d + 1.f, 1e-12f));
}

// weight repack (bf16, fragment-coalesced) + t_cm K-pad zeroing
__global__ void k_prep(const float* __restrict__ cnn_w, const float* __restrict__ up_w,
                       const float* __restrict__ gcn_w, const float* __restrict__ dec_w,
                       const float* __restrict__ pred_w,
                       unsigned short* __restrict__ bt_cnn, unsigned short* __restrict__ bt_up,
                       unsigned short* __restrict__ bt_gcn, unsigned short* __restrict__ bt_dec,
                       unsigned short* __restrict__ bt_pred, unsigned short* __restrict__ tcm)
{
  long i = (long)blockIdx.x * 256 + threadIdx.x;
  long n = 4L*589824;
  if (i < n) {  // [tap][c][n16][kchunk][nl][ke]
    const long l = i / 589824, r = i % 589824;
    const long tap = r >> 16, r2 = r & 65535;
    const long c = r2 >> 13, n16 = (r2 >> 9) & 15, kchunk = (r2 >> 7) & 3;
    const long nl = (r2 >> 3) & 15, ke = r2 & 7;
    const long co = n16*16 + nl, ci = c*32 + kchunk*8 + ke;
    bt_cnn[i] = f2bf(cnn_w[(((l*256+co)*256+ci)*3 + tap/3)*3 + (tap%3)]);
    return;
  }
  i -= n; n = 2L*589824;
  if (i < n) {
    const long l = i / 589824, r = i % 589824;
    const long tap = r >> 16, r2 = r & 65535;
    const long c = r2 >> 13, n16 = (r2 >> 9) & 15, kchunk = (r2 >> 7) & 3;
    const long nl = (r2 >> 3) & 15, ke = r2 & 7;
    const long co = n16*16 + nl, ci = c*32 + kchunk*8 + ke;
    bt_up[i] = f2bf(up_w[(((l*256+co)*256+ci)*3 + tap/3)*3 + (tap%3)]);
    return;
  }
  i -= n; n = 2L*256*256;
  if (i < n) {  // Bt_gcn[l][co][ci] = gcn_w[l][ci][co]
    const long ci = i & 255, co = (i >> 8) & 255, l = i >> 16;
    bt_gcn[i] = f2bf(gcn_w[(l*256 + ci)*256 + co]);
    return;
  }
  i -= n; n = 262144;
  if (i < n) {  // dec packed [tap][c][g16][k4][nl][ke]
    const long ke = i&7, nl = (i>>3)&15, k4 = (i>>7)&3, g = (i>>9)&15;
    const long c = (i>>13)&7, tap = i>>16;
    const long co = g*16 + nl, ci = c*32 + k4*8 + ke;
    bt_dec[i] = f2bf(dec_w[((ci*256 + co)*2 + (tap>>1))*2 + (tap&1)]);
    return;
  }
  i -= n; n = 32768;
  if (i < n) {  // pred packed [c][g8][k4][nl][ke], cls>=80 -> 0
    const long ke = i&7, nl = (i>>3)&15, k4 = (i>>7)&3, g = (i>>9)&7, c = i>>12;
    const long cls = g*16 + nl, ci = c*32 + k4*8 + ke;
    bt_pred[i] = (cls < 80) ? f2bf(pred_w[cls*256 + ci]) : (unsigned short)0;
    return;
  }
  i -= n; n = 512L*256*28;
  if (i < n) {  // t_cm[b][c][196..223] = 0
    const long p = 196 + (i % 28);
    const long rest = i / 28;
    const long c = rest & 255, bb = rest >> 8;
    tcm[((size_t)(bb*256 + c))*NPAD + p] = 0;
    return;
  }
}

// ---------------------------------------------------------------------------
extern "C" void kernel_launch(void* const* d_in, const int* in_sizes, int n_in,
                              void* d_out, int out_size, void* d_ws, size_t ws_size,
                              hipStream_t stream)
{
  const float* features = (const float*)d_in[0];
  const float* cnn_w  = (const float*)d_in[1];
  const float* cnn_b  = (const float*)d_in[2];
  const float* gcn_w  = (const float*)d_in[3];
  const float* gcn_b  = (const float*)d_in[4];
  const float* up_w   = (const float*)d_in[5];
  const float* up_b   = (const float*)d_in[6];
  const float* dec_w  = (const float*)d_in[7];
  const float* dec_b  = (const float*)d_in[8];
  const float* pred_w = (const float*)d_in[9];
  const float* pred_b = (const float*)d_in[10];

  char* ws = (char*)d_ws;
  size_t o = 0;
  auto take = [&](size_t nbytes) -> char* {
    char* p = ws + o;
    o += (nbytes + 255) & ~(size_t)255;
    return p;
  };
  unsigned short* bt_cnn  = (unsigned short*)take(4L*589824*2);
  unsigned short* bt_up   = (unsigned short*)take(2L*589824*2);
  unsigned short* bt_gcn  = (unsigned short*)take(2L*256*256*2);
  unsigned short* bt_dec  = (unsigned short*)take(262144L*2);
  unsigned short* bt_pred = (unsigned short*)take(32768L*2);
  unsigned short* actA    = (unsigned short*)take((size_t)MTOT*256*2);
  unsigned short* actB    = (unsigned short*)take((size_t)MTOT*256*2);
  unsigned short* ahat    = (unsigned short*)take((size_t)B_N*NPAD*NPAD*2);
  unsigned short* tcm     = (unsigned short*)take((size_t)B_N*256*NPAD*2);
  float*          Sbuf    = (float*)take((size_t)B_N*256*4);
  float*          dinvb   = (float*)take((size_t)MTOT*4);

  float* mask  = (float*)d_out;
  float* feats = mask + (size_t)B_N*80*28*28;

  const dim3 blk(256);
  const dim3 gc(784);                // conv: 1-D, XCD-swizzled in-kernel
  const dim3 gg(MTOT/128, 2);        // 784 x 2
  const dim3 gs(2, 2, B_N);

  k_prep<<<29824, blk, 0, stream>>>(cnn_w, up_w, gcn_w, dec_w, pred_w,
                                    bt_cnn, bt_up, bt_gcn, bt_dec, bt_pred, tcm);
  k_tin<<<dim3(B_N, 7, 8), blk, 0, stream>>>(features, actA);

  // CNN stack (4x conv3x3+relu), ping-pong actA/actB
  gemm_conv<0><<<gc, dim3(512), 0, stream>>>(actA, bt_cnn + 0L*589824, actB, nullptr, cnn_b + 0);
  gemm_conv<0><<<gc, dim3(512), 0, stream>>>(actB, bt_cnn + 1L*589824, actA, nullptr, cnn_b + 256);
  gemm_conv<0><<<gc, dim3(512), 0, stream>>>(actA, bt_cnn + 2L*589824, actB, nullptr, cnn_b + 512);
  gemm_conv<0><<<gc, dim3(512), 0, stream>>>(actB, bt_cnn + 3L*589824, actA, nullptr, cnn_b + 768);
  // f = actA

  // cosine adjacency with fused normalization
  k_fnnorm<<<MTOT/4, blk, 0, stream>>>(actA, actB);     // fn = actB
  k_ssum<<<B_N, blk, 0, stream>>>(actB, Sbuf);
  k_dinv<<<MTOT/4, blk, 0, stream>>>(actB, Sbuf, dinvb);
  gemm_s<4,8><<<gs, blk, 0, stream>>>(actB, NPIX, 256, (long)MTOT-1,
                                      actB, NPIX, 256, (long)MTOT-1, ahat, dinvb);

  // GCN layer 1: t = g @ W1 (channel-major), g1 = gelu(A_hat @ t + b1)
  gemm_g<8,2><<<gg, blk, 0, stream>>>(actA, bt_gcn, tcm, nullptr, nullptr, 0,0);
  gemm_s<5,7><<<gs, blk, 0, stream>>>(ahat, NPAD, NPAD, (long)B_N*NPAD-1,
                                      tcm, 256, NPAD, (long)B_N*256-1, actB, gcn_b);
  // GCN layer 2
  gemm_g<8,2><<<gg, blk, 0, stream>>>(actB, bt_gcn + 65536, tcm, nullptr, nullptr, 0,0);
  gemm_s<5,7><<<gs, blk, 0, stream>>>(ahat, NPAD, NPAD, (long)B_N*NPAD-1,
                                      tcm, 256, NPAD, (long)B_N*256-1, actA, gcn_b + 256);

  // Upsample head convs; second one also writes fp32 feats (output 1)
  gemm_conv<0><<<gc, dim3(512), 0, stream>>>(actA, bt_up + 0L*589824, actB, nullptr, up_b + 0);
  gemm_conv<1><<<gc, dim3(512), 0, stream>>>(actB, bt_up + 1L*589824, actA, feats,   up_b + 256);

  // Fused ConvTranspose(k2,s2)+ReLU+pred(1x1), 256-thread / M-tile-32 blocks
  k_decpred<<<dim3(MTOT/32), blk, 0, stream>>>(actA, bt_dec, bt_pred,
                                               dec_b, pred_b, mask);
}

// Round 11
// 1434.642 us; speedup vs baseline: 1.5922x; 1.1918x over previous
//
#include <hip/hip_runtime.h>
#include <stdint.h>

typedef __attribute__((ext_vector_type(8))) short short8;
typedef __attribute__((ext_vector_type(4))) float f32x4;

#define B_N   512
#define NPIX  196
#define MTOT  (B_N*NPIX)     // 100352
#define NPAD  224            // padded pixel dim for adjacency GEMMs

static_assert(MTOT % 128 == 0, "M must tile by 128");

__device__ __forceinline__ float bf2f(unsigned short u){
  unsigned int x = ((unsigned int)u) << 16;
  return __builtin_bit_cast(float, x);
}
__device__ __forceinline__ unsigned short f2bf(float f){
  unsigned int x = __builtin_bit_cast(unsigned int, f);
  x += 0x7fffu + ((x >> 16) & 1u);          // RNE
  return (unsigned short)(x >> 16);
}
__device__ __forceinline__ void gload16(const void* g, void* l){
  __builtin_amdgcn_global_load_lds(
    (const __attribute__((address_space(1))) void*)(uintptr_t)g,
    (__attribute__((address_space(3))) void*)(uintptr_t)l, 16, 0, 0);
}
__device__ __forceinline__ float gelu_exact(float x){
  return 0.5f * x * (1.f + erff(x * 0.70710678118654752440f));
}

// ---------------------------------------------------------------------------
// 3x3 conv as implicit-im2col GEMM (round-8 structure, unchanged).
// Block tile 128x256, 512 threads = 8 waves (2M x 4N), wave tile 64x64.
// A: 160-row LDS halo via global_load_lds, dbuf per chunk; B: direct
// global->VGPR packed fragments. Zero-row address-select. 2-way swizzle.
// ---------------------------------------------------------------------------
template<int EPI>
__global__ __launch_bounds__(512, 4) void gemm_conv(
    const unsigned short* __restrict__ A, const unsigned short* __restrict__ Bt,
    unsigned short* __restrict__ outb, float* __restrict__ outf,
    const float* __restrict__ bias)
{
  __shared__ __align__(16) char smem[2*10240 + 64];   // A halo dbuf + zero row
  const int tid = threadIdx.x;
  const int wid = tid >> 6, lane = tid & 63;
  const int wr = wid >> 2, wn = wid & 3;              // 2M x 4N wave grid
  // XCD-chunked swizzle: 784 = 8 * 98 exactly
  const int orig = blockIdx.x;
  const int vid = (orig & 7) * 98 + (orig >> 3);
  const int m0 = vid * 128;

  const int ssw = ((lane & 3) ^ ((lane >> 3) & 3)) << 4;  // stage-source slot
  const int s16 = (lane >> 4) << 4;                       // logical 16B slot

  if (tid < 16) ((int*)(smem + 20480))[tid] = 0;          // zero row

  auto stageA = [&](int cc, char* dst){
#pragma unroll
    for (int s = 0; s < 2; ++s) {
      const int g = wid + s*8;
      if (g < 10) {
        const int r = g*16 + (lane >> 2);
        long gr = (long)m0 - 16 + r;
        if (gr < 0) gr = 0;
        if (gr >= MTOT) gr = MTOT - 1;
        gload16((const char*)A + (size_t)gr*512 + (size_t)cc*64 + (size_t)ssw,
                dst + g*1024);
      }
    }
  };

  f32x4 acc[4][4];
#pragma unroll
  for (int i=0;i<4;i++)
#pragma unroll
    for (int j=0;j<4;j++) acc[i][j] = (f32x4){0.f,0.f,0.f,0.f};

  int arow[4]; unsigned hh[4], ww[4];
#pragma unroll
  for (int i=0;i<4;i++){
    const int ml = wr*64 + i*16 + (lane&15);
    arow[i] = ml + 16;                       // LDS halo row for doff=0
    const int p = (m0 + ml) % NPIX;
    hh[i] = (unsigned)(p / 14); ww[i] = (unsigned)(p % 14);
  }

  // B fragment base: packed layout [tap][c][n16][kchunk][nl][ke]
  const unsigned short* bbase = Bt + ((size_t)(wn*4)*64 + lane)*8;
  const char* pz = smem + 20480 + s16;       // zero-row base

  stageA(0, smem);
  __syncthreads();

#pragma unroll 1
  for (int c = 0; c < 8; ++c) {
    if (c < 7) stageA(c+1, smem + ((c+1)&1)*10240);
    const char* aB = smem + (c&1)*10240;
#pragma unroll 3
    for (int tap = 0; tap < 9; ++tap) {
      const unsigned short* bp = bbase + (size_t)(tap*8 + c)*8192;
      short8 bv[4];
#pragma unroll
      for (int j=0;j<4;j++) bv[j] = *(const short8*)(bp + j*512);
      const int dh = tap/3 - 1, dw = tap - (tap/3)*3 - 1;
      const int doff = dh*14 + dw;
      short8 av[4];
#pragma unroll
      for (int i=0;i<4;i++){
        const int r = arow[i] + doff;
        const char* pa = aB + r*64 + (s16 ^ (((r>>1)&3)<<4));
        const bool val = (hh[i] + (unsigned)dh < 14u) && (ww[i] + (unsigned)dw < 14u);
        av[i] = *(const short8*)(val ? pa : pz);
      }
#pragma unroll
      for (int i=0;i<4;i++)
#pragma unroll
        for (int j=0;j<4;j++)
          acc[i][j] = __builtin_amdgcn_mfma_f32_16x16x32_bf16(av[i], bv[j], acc[i][j], 0,0,0);
    }
    __syncthreads();   // stageA(c+1) drain + WAR guard
  }

#pragma unroll
  for (int i=0;i<4;i++){
#pragma unroll
    for (int j=0;j<4;j++){
#pragma unroll
      for (int r=0;r<4;r++){
        const int row = m0 + wr*64 + i*16 + ((lane>>4)<<2) + r;
        const int col = wn*64 + j*16 + (lane&15);
        float v = acc[i][j][r] + bias[col];
        v = fmaxf(v, 0.f);
        outb[(size_t)row*256 + col] = f2bf(v);
        if constexpr (EPI == 1) {
          const int b = row / NPIX, p = row - b*NPIX;
          outf[((size_t)b*256 + col)*NPIX + p] = v;
        }
      }
    }
  }
}

// ---------------------------------------------------------------------------
// Fused ConvTranspose(k2,s2)+ReLU+pred(1x1)+bias (round-8 verbatim: the
// known-good 199us config). 512 threads, M-tile 64, sA 32KB + sD 32KB.
// R9 (reg-A @512,8) and R10 (256thr @256,4) both proved VGPR-infeasible:
// the fused body needs ~128 unified VGPRs -> 2 blocks/CU is the wall.
// ---------------------------------------------------------------------------
__global__ __launch_bounds__(512) void k_decpred(
    const unsigned short* __restrict__ A, const unsigned short* __restrict__ Bdec,
    const unsigned short* __restrict__ Bpred, const float* __restrict__ decb,
    const float* __restrict__ predb, float* __restrict__ mask)
{
  __shared__ __align__(16) char smem[65536];
  char* sA = smem;            // [8 chunks][64 rows][64B], XOR-swizzled
  char* sD = smem + 32768;    // [64 rows][512B] bf16 dec-out, swizzled
  const int tid = threadIdx.x;
  const int wid = tid >> 6, lane = tid & 63;
  const int m0 = blockIdx.x * 64;
  const int ssw = ((lane & 3) ^ ((lane >> 3) & 3)) << 4;
  const int s16 = (lane >> 4) << 4;
  const int wr = wid >> 2, wn = wid & 3;

#pragma unroll
  for (int p = 0; p < 4; ++p) {
    const int cc = p*2 + (wid >> 2);
    const int r  = (wid & 3)*16 + (lane >> 2);
    gload16((const char*)A + (size_t)(m0 + r)*512 + (size_t)cc*64 + (size_t)ssw,
            sA + cc*4096 + (wid & 3)*1024);
  }

  float bd[4];
#pragma unroll
  for (int j = 0; j < 4; ++j) bd[j] = decb[wn*64 + j*16 + (lane & 15)];
  float pb[2]; int pcol[2];
#pragma unroll
  for (int j = 0; j < 2; ++j) {
    pcol[j] = wn*32 + j*16 + (lane & 15);
    pb[j] = (pcol[j] < 80) ? predb[pcol[j]] : 0.f;
  }

  __syncthreads();

#pragma unroll 1
  for (int th = 0; th < 2; ++th) {
    f32x4 accP[2][2][2];   // [tw][i][j]
#pragma unroll
    for (int tw = 0; tw < 2; ++tw) {
      const int tap = th*2 + tw;
      f32x4 acc[2][4];
#pragma unroll
      for (int i=0;i<2;i++)
#pragma unroll
        for (int j=0;j<4;j++) acc[i][j] = (f32x4){0.f,0.f,0.f,0.f};
#pragma unroll
      for (int c = 0; c < 8; ++c) {
        short8 bv[4];
#pragma unroll
        for (int j=0;j<4;j++)
          bv[j] = *(const short8*)(Bdec + (size_t)((tap*8+c)*16 + wn*4+j)*512 + lane*8);
        short8 av[2];
#pragma unroll
        for (int i=0;i<2;i++){
          const int rA = wr*32 + i*16 + (lane&15);
          av[i] = *(const short8*)(sA + c*4096 + rA*64 + (s16 ^ (((rA>>1)&3)<<4)));
        }
#pragma unroll
        for (int i=0;i<2;i++)
#pragma unroll
          for (int j=0;j<4;j++)
            acc[i][j] = __builtin_amdgcn_mfma_f32_16x16x32_bf16(av[i], bv[j], acc[i][j],0,0,0);
      }
#pragma unroll
      for (int i=0;i<2;i++)
#pragma unroll
        for (int j=0;j<4;j++)
#pragma unroll
          for (int rr=0;rr<4;rr++){
            const int row = wr*32 + i*16 + ((lane>>4)<<2) + rr;
            const int colL = wn*64 + j*16 + (lane&15);
            const float v = fmaxf(acc[i][j][rr] + bd[j], 0.f);
            *(unsigned short*)(sD + row*512 + ((colL<<1) ^ ((row&7)<<4))) = f2bf(v);
          }
      __syncthreads();
#pragma unroll
      for (int i=0;i<2;i++)
#pragma unroll
        for (int j=0;j<2;j++) accP[tw][i][j] = (f32x4){0.f,0.f,0.f,0.f};
#pragma unroll
      for (int c = 0; c < 8; ++c) {
        short8 bp2[2];
#pragma unroll
        for (int j=0;j<2;j++)
          bp2[j] = *(const short8*)(Bpred + (size_t)(c*8 + wn*2+j)*512 + lane*8);
        short8 ap[2];
#pragma unroll
        for (int i=0;i<2;i++){
          const int rP = wr*32 + i*16 + (lane&15);
          ap[i] = *(const short8*)(sD + rP*512 + ((c*64 + s16) ^ ((rP&7)<<4)));
        }
#pragma unroll
        for (int i=0;i<2;i++)
#pragma unroll
          for (int j=0;j<2;j++)
            accP[tw][i][j] = __builtin_amdgcn_mfma_f32_16x16x32_bf16(ap[i], bp2[j], accP[tw][i][j],0,0,0);
      }
      __syncthreads();
    }
#pragma unroll
    for (int i=0;i<2;i++)
#pragma unroll
      for (int j=0;j<2;j++){
        if (pcol[j] < 80) {
#pragma unroll
          for (int rr=0;rr<4;rr++){
            const int row = m0 + wr*32 + i*16 + ((lane>>4)<<2) + rr;
            const int b = row / NPIX, p = row - b*NPIX;
            const int hh = p/14, w2 = p - hh*14;
            float2 v2;
            v2.x = accP[0][i][j][rr] + pb[j];
            v2.y = accP[1][i][j][rr] + pb[j];
            *(float2*)&mask[(((size_t)b*80 + pcol[j])*28 + 2*hh + th)*28 + 2*w2] = v2;
          }
        }
      }
  }
}

// ---------------------------------------------------------------------------
// Global-M 1-tap GEMM (GCN xW). EPI 2: plain -> t_cm bf16 [(b*256+n)*224+p]
// ---------------------------------------------------------------------------
template<int KI, int EPI>
__global__ __launch_bounds__(256) void gemm_g(
    const unsigned short* __restrict__ A, const unsigned short* __restrict__ Bt,
    unsigned short* __restrict__ outb, float* __restrict__ outf,
    const float* __restrict__ bias, int th, int tw)
{
  __shared__ __align__(16) char smem[16384];
  char* sA = smem; char* sB = smem + 8192;
  const int tid = threadIdx.x;
  const int wid = tid >> 6, lane = tid & 63;
  const int wr = wid >> 1, wc = wid & 1;
  const int m0 = blockIdx.x * 128, n0 = blockIdx.y * 128;
  const int rs = wid*16 + (lane >> 2);
  const int ssw = ((lane & 3) ^ ((lane >> 3) & 3)) << 4;
  char* dA0 = sA + wid*1024; char* dA1 = sA + 4096 + wid*1024;
  char* dB0 = sB + wid*1024; char* dB1 = sB + 4096 + wid*1024;
  const char* pA0 = (const char*)(A + (size_t)(m0 + rs)      * (KI*32));
  const char* pA1 = (const char*)(A + (size_t)(m0 + rs + 64) * (KI*32));
  const char* pB0 = (const char*)(Bt + (size_t)(n0 + rs)      * (KI*32));
  const char* pB1 = (const char*)(Bt + (size_t)(n0 + rs + 64) * (KI*32));

  f32x4 acc[4][4];
#pragma unroll
  for (int i=0;i<4;i++)
#pragma unroll
    for (int j=0;j<4;j++) acc[i][j] = (f32x4){0.f,0.f,0.f,0.f};

  const int s16 = (lane >> 4) << 4;

#pragma unroll 1
  for (int kk = 0; kk < KI; ++kk) {
    const int ko = kk*64 + ssw;
    gload16(pA0 + ko, dA0);
    gload16(pA1 + ko, dA1);
    gload16(pB0 + ko, dB0);
    gload16(pB1 + ko, dB1);
    __syncthreads();
    short8 av[4], bv[4];
#pragma unroll
    for (int i=0;i<4;i++){
      const int ra = wr*64 + i*16 + (lane&15);
      const int rb = wc*64 + i*16 + (lane&15);
      av[i] = *(const short8*)(sA + ra*64 + (s16 ^ (((ra>>1)&3)<<4)));
      bv[i] = *(const short8*)(sB + rb*64 + (s16 ^ (((rb>>1)&3)<<4)));
    }
#pragma unroll
    for (int i=0;i<4;i++)
#pragma unroll
      for (int j=0;j<4;j++)
        acc[i][j] = __builtin_amdgcn_mfma_f32_16x16x32_bf16(av[i], bv[j], acc[i][j], 0,0,0);
    __syncthreads();
  }

#pragma unroll
  for (int i=0;i<4;i++){
#pragma unroll
    for (int j=0;j<4;j++){
#pragma unroll
      for (int r=0;r<4;r++){
        const int row = m0 + wr*64 + i*16 + ((lane>>4)<<2) + r;
        const int col = n0 + wc*64 + j*16 + (lane&15);
        float v = acc[i][j][r];
        if constexpr (EPI == 0) {
          v += bias[col];
          v = fmaxf(v, 0.f);
          outb[(size_t)row*256 + col] = f2bf(v);
        } else if constexpr (EPI == 2) {
          const int b = row / NPIX, p = row - b*NPIX;
          outb[((size_t)b*256 + col)*NPAD + p] = f2bf(v);
        }
      }
    }
  }
}

// ---------------------------------------------------------------------------
// Per-sample GEMM. EPI 4: adjacency with FUSED sym-normalization.
// EPI 5: gelu(acc + bias) -> bf16 act
// ---------------------------------------------------------------------------
template<int EPI, int KI>
__global__ __launch_bounds__(256) void gemm_s(
    const unsigned short* __restrict__ Asrc, int a_rps, int a_stride, long amax,
    const unsigned short* __restrict__ Bsrc, int b_rps, int b_stride, long bmax,
    unsigned short* __restrict__ outb, const float* __restrict__ bias)
{
  __shared__ __align__(16) char smem[16384];
  char* sA = smem; char* sB = smem + 8192;
  const int tid = threadIdx.x;
  const int wid = tid >> 6, lane = tid & 63;
  const int wr = wid >> 1, wc = wid & 1;
  const int m0 = blockIdx.x * 128, n0 = blockIdx.y * 128;
  const int b  = blockIdx.z;
  const int rs = wid*16 + (lane >> 2);
  const int ssw = ((lane & 3) ^ ((lane >> 3) & 3)) << 4;
  char* dA0 = sA + wid*1024; char* dA1 = sA + 4096 + wid*1024;
  char* dB0 = sB + wid*1024; char* dB1 = sB + 4096 + wid*1024;
  long ar0 = (long)b*a_rps + m0 + rs;       if (ar0 > amax) ar0 = amax;
  long ar1 = (long)b*a_rps + m0 + rs + 64;  if (ar1 > amax) ar1 = amax;
  long br0 = (long)b*b_rps + n0 + rs;       if (br0 > bmax) br0 = bmax;
  long br1 = (long)b*b_rps + n0 + rs + 64;  if (br1 > bmax) br1 = bmax;
  const char* pA0  = (const char*)(Asrc + ar0 * a_stride);
  const char* pA1  = (const char*)(Asrc + ar1 * a_stride);
  const char* pBt0 = (const char*)(Bsrc + br0 * b_stride);
  const char* pBt1 = (const char*)(Bsrc + br1 * b_stride);

  f32x4 acc[4][4];
#pragma unroll
  for (int i=0;i<4;i++)
#pragma unroll
    for (int j=0;j<4;j++) acc[i][j] = (f32x4){0.f,0.f,0.f,0.f};

  const int s16 = (lane >> 4) << 4;

#pragma unroll 1
  for (int kk = 0; kk < KI; ++kk) {
    const int ko = kk*64 + ssw;
    gload16(pA0 + ko, dA0);
    gload16(pA1 + ko, dA1);
    gload16(pBt0 + ko, dB0);
    gload16(pBt1 + ko, dB1);
    __syncthreads();
    short8 av[4], bv[4];
#pragma unroll
    for (int i=0;i<4;i++){
      const int ra = wr*64 + i*16 + (lane&15);
      const int rb = wc*64 + i*16 + (lane&15);
      av[i] = *(const short8*)(sA + ra*64 + (s16 ^ (((ra>>1)&3)<<4)));
      bv[i] = *(const short8*)(sB + rb*64 + (s16 ^ (((rb>>1)&3)<<4)));
    }
#pragma unroll
    for (int i=0;i<4;i++)
#pragma unroll
      for (int j=0;j<4;j++)
        acc[i][j] = __builtin_amdgcn_mfma_f32_16x16x32_bf16(av[i], bv[j], acc[i][j], 0,0,0);
    __syncthreads();
  }

  if constexpr (EPI == 4) {
    int nlv[4]; float dn[4];
#pragma unroll
    for (int j=0;j<4;j++){
      nlv[j] = n0 + wc*64 + j*16 + (lane&15);
      dn[j] = (nlv[j] < NPIX) ? bias[(size_t)b*NPIX + nlv[j]] : 0.f;
    }
#pragma unroll
    for (int i=0;i<4;i++){
#pragma unroll
      for (int r=0;r<4;r++){
        const int ml = m0 + wr*64 + i*16 + ((lane>>4)<<2) + r;
        const float dmv = (ml < NPIX) ? bias[(size_t)b*NPIX + ml] : 0.f;
        if (ml < NPAD) {
#pragma unroll
          for (int j=0;j<4;j++){
            if (nlv[j] < NPAD) {
              const float o = (acc[i][j][r] + ((ml==nlv[j]) ? 1.f : 0.f)) * dmv * dn[j];
              outb[((size_t)b*NPAD + ml)*NPAD + nlv[j]] = f2bf(o);
            }
          }
        }
      }
    }
  } else {  // EPI 5
#pragma unroll
    for (int i=0;i<4;i++){
#pragma unroll
      for (int j=0;j<4;j++){
#pragma unroll
        for (int r=0;r<4;r++){
          const int ml = m0 + wr*64 + i*16 + ((lane>>4)<<2) + r;
          const int nl = n0 + wc*64 + j*16 + (lane&15);
          if (ml < NPIX) {
            const float x = acc[i][j][r] + bias[nl];
            outb[((size_t)b*NPIX + ml)*256 + nl] = f2bf(gelu_exact(x));
          }
        }
      }
    }
  }
}

// --------------------------- small kernels --------------------------------

// NCHW fp32 -> pixel-major bf16 [B*196, 256]
__global__ void k_tin(const float* __restrict__ in, unsigned short* __restrict__ out)
{
  __shared__ float t[32][29];
  const int b = blockIdx.x, p0 = blockIdx.y * 28, c0 = blockIdx.z * 32;
  const int tid = threadIdx.x;
  for (int i = tid; i < 896; i += 256) {
    const int c = i / 28, p = i - c*28;
    t[c][p] = in[((size_t)b*256 + c0 + c)*196 + p0 + p];
  }
  __syncthreads();
  for (int i = tid; i < 896; i += 256) {
    const int p = i >> 5, c = i & 31;
    out[((size_t)b*196 + p0 + p)*256 + c0 + c] = f2bf(t[c][p]);
  }
}

// row-wise L2 normalize: fn = f / max(||f||, 1e-8), one wave per row
__global__ void k_fnnorm(const unsigned short* __restrict__ f, unsigned short* __restrict__ fn)
{
  const int row  = blockIdx.x * 4 + (threadIdx.x >> 6);
  const int lane = threadIdx.x & 63;
  const unsigned short* src = f + (size_t)row*256 + lane*4;
  const float x0 = bf2f(src[0]), x1 = bf2f(src[1]), x2 = bf2f(src[2]), x3 = bf2f(src[3]);
  float s = x0*x0 + x1*x1 + x2*x2 + x3*x3;
#pragma unroll
  for (int o = 32; o > 0; o >>= 1) s += __shfl_xor(s, o, 64);
  const float scale = 1.f / fmaxf(sqrtf(s), 1e-8f);
  unsigned short* dst = fn + (size_t)row*256 + lane*4;
  dst[0]=f2bf(x0*scale); dst[1]=f2bf(x1*scale); dst[2]=f2bf(x2*scale); dst[3]=f2bf(x3*scale);
}

// S[b][c] = sum_p fn[b][p][c]
__global__ void k_ssum(const unsigned short* __restrict__ fn, float* __restrict__ S)
{
  const int b = blockIdx.x, c = threadIdx.x;
  const unsigned short* p = fn + (size_t)b*NPIX*256 + c;
  float s = 0.f;
  for (int i = 0; i < NPIX; ++i) s += bf2f(p[(size_t)i*256]);
  S[b*256 + c] = s;
}

// dinv[row] = rsqrt(max(fn[row].S[b] + 1, 1e-12))
__global__ void k_dinv(const unsigned short* __restrict__ fn, const float* __restrict__ S,
                       float* __restrict__ dinv)
{
  const int row  = blockIdx.x * 4 + (threadIdx.x >> 6);
  const int lane = threadIdx.x & 63;
  const int b = row / NPIX;
  const unsigned short* p = fn + (size_t)row*256 + lane*4;
  const float* sp = S + b*256 + lane*4;
  float d = bf2f(p[0])*sp[0] + bf2f(p[1])*sp[1] + bf2f(p[2])*sp[2] + bf2f(p[3])*sp[3];
#pragma unroll
  for (int o = 32; o > 0; o >>= 1) d += __shfl_xor(d, o, 64);
  if (lane == 0) dinv[row] = rsqrtf(fmaxf(d + 1.f, 1e-12f));
}

// weight repack (bf16, fragment-coalesced) + t_cm K-pad zeroing
__global__ void k_prep(const float* __restrict__ cnn_w, const float* __restrict__ up_w,
                       const float* __restrict__ gcn_w, const float* __restrict__ dec_w,
                       const float* __restrict__ pred_w,
                       unsigned short* __restrict__ bt_cnn, unsigned short* __restrict__ bt_up,
                       unsigned short* __restrict__ bt_gcn, unsigned short* __restrict__ bt_dec,
                       unsigned short* __restrict__ bt_pred, unsigned short* __restrict__ tcm)
{
  long i = (long)blockIdx.x * 256 + threadIdx.x;
  long n = 4L*589824;
  if (i < n) {  // [tap][c][n16][kchunk][nl][ke]
    const long l = i / 589824, r = i % 589824;
    const long tap = r >> 16, r2 = r & 65535;
    const long c = r2 >> 13, n16 = (r2 >> 9) & 15, kchunk = (r2 >> 7) & 3;
    const long nl = (r2 >> 3) & 15, ke = r2 & 7;
    const long co = n16*16 + nl, ci = c*32 + kchunk*8 + ke;
    bt_cnn[i] = f2bf(cnn_w[(((l*256+co)*256+ci)*3 + tap/3)*3 + (tap%3)]);
    return;
  }
  i -= n; n = 2L*589824;
  if (i < n) {
    const long l = i / 589824, r = i % 589824;
    const long tap = r >> 16, r2 = r & 65535;
    const long c = r2 >> 13, n16 = (r2 >> 9) & 15, kchunk = (r2 >> 7) & 3;
    const long nl = (r2 >> 3) & 15, ke = r2 & 7;
    const long co = n16*16 + nl, ci = c*32 + kchunk*8 + ke;
    bt_up[i] = f2bf(up_w[(((l*256+co)*256+ci)*3 + tap/3)*3 + (tap%3)]);
    return;
  }
  i -= n; n = 2L*256*256;
  if (i < n) {  // Bt_gcn[l][co][ci] = gcn_w[l][ci][co]
    const long ci = i & 255, co = (i >> 8) & 255, l = i >> 16;
    bt_gcn[i] = f2bf(gcn_w[(l*256 + ci)*256 + co]);
    return;
  }
  i -= n; n = 262144;
  if (i < n) {  // dec packed [tap][c][g16][k4][nl][ke]
    const long ke = i&7, nl = (i>>3)&15, k4 = (i>>7)&3, g = (i>>9)&15;
    const long c = (i>>13)&7, tap = i>>16;
    const long co = g*16 + nl, ci = c*32 + k4*8 + ke;
    bt_dec[i] = f2bf(dec_w[((ci*256 + co)*2 + (tap>>1))*2 + (tap&1)]);
    return;
  }
  i -= n; n = 32768;
  if (i < n) {  // pred packed [c][g8][k4][nl][ke], cls>=80 -> 0
    const long ke = i&7, nl = (i>>3)&15, k4 = (i>>7)&3, g = (i>>9)&7, c = i>>12;
    const long cls = g*16 + nl, ci = c*32 + k4*8 + ke;
    bt_pred[i] = (cls < 80) ? f2bf(pred_w[cls*256 + ci]) : (unsigned short)0;
    return;
  }
  i -= n; n = 512L*256*28;
  if (i < n) {  // t_cm[b][c][196..223] = 0
    const long p = 196 + (i % 28);
    const long rest = i / 28;
    const long c = rest & 255, bb = rest >> 8;
    tcm[((size_t)(bb*256 + c))*NPAD + p] = 0;
    return;
  }
}

// ---------------------------------------------------------------------------
extern "C" void kernel_launch(void* const* d_in, const int* in_sizes, int n_in,
                              void* d_out, int out_size, void* d_ws, size_t ws_size,
                              hipStream_t stream)
{
  const float* features = (const float*)d_in[0];
  const float* cnn_w  = (const float*)d_in[1];
  const float* cnn_b  = (const float*)d_in[2];
  const float* gcn_w  = (const float*)d_in[3];
  const float* gcn_b  = (const float*)d_in[4];
  const float* up_w   = (const float*)d_in[5];
  const float* up_b   = (const float*)d_in[6];
  const float* dec_w  = (const float*)d_in[7];
  const float* dec_b  = (const float*)d_in[8];
  const float* pred_w = (const float*)d_in[9];
  const float* pred_b = (const float*)d_in[10];

  char* ws = (char*)d_ws;
  size_t o = 0;
  auto take = [&](size_t nbytes) -> char* {
    char* p = ws + o;
    o += (nbytes + 255) & ~(size_t)255;
    return p;
  };
  unsigned short* bt_cnn  = (unsigned short*)take(4L*589824*2);
  unsigned short* bt_up   = (unsigned short*)take(2L*589824*2);
  unsigned short* bt_gcn  = (unsigned short*)take(2L*256*256*2);
  unsigned short* bt_dec  = (unsigned short*)take(262144L*2);
  unsigned short* bt_pred = (unsigned short*)take(32768L*2);
  unsigned short* actA    = (unsigned short*)take((size_t)MTOT*256*2);
  unsigned short* actB    = (unsigned short*)take((size_t)MTOT*256*2);
  unsigned short* ahat    = (unsigned short*)take((size_t)B_N*NPAD*NPAD*2);
  unsigned short* tcm     = (unsigned short*)take((size_t)B_N*256*NPAD*2);
  float*          Sbuf    = (float*)take((size_t)B_N*256*4);
  float*          dinvb   = (float*)take((size_t)MTOT*4);

  float* mask  = (float*)d_out;
  float* feats = mask + (size_t)B_N*80*28*28;

  const dim3 blk(256);
  const dim3 gc(784);                // conv: 1-D, XCD-swizzled in-kernel
  const dim3 gg(MTOT/128, 2);        // 784 x 2
  const dim3 gs(2, 2, B_N);

  k_prep<<<29824, blk, 0, stream>>>(cnn_w, up_w, gcn_w, dec_w, pred_w,
                                    bt_cnn, bt_up, bt_gcn, bt_dec, bt_pred, tcm);
  k_tin<<<dim3(B_N, 7, 8), blk, 0, stream>>>(features, actA);

  // CNN stack (4x conv3x3+relu), ping-pong actA/actB
  gemm_conv<0><<<gc, dim3(512), 0, stream>>>(actA, bt_cnn + 0L*589824, actB, nullptr, cnn_b + 0);
  gemm_conv<0><<<gc, dim3(512), 0, stream>>>(actB, bt_cnn + 1L*589824, actA, nullptr, cnn_b + 256);
  gemm_conv<0><<<gc, dim3(512), 0, stream>>>(actA, bt_cnn + 2L*589824, actB, nullptr, cnn_b + 512);
  gemm_conv<0><<<gc, dim3(512), 0, stream>>>(actB, bt_cnn + 3L*589824, actA, nullptr, cnn_b + 768);
  // f = actA

  // cosine adjacency with fused normalization
  k_fnnorm<<<MTOT/4, blk, 0, stream>>>(actA, actB);     // fn = actB
  k_ssum<<<B_N, blk, 0, stream>>>(actB, Sbuf);
  k_dinv<<<MTOT/4, blk, 0, stream>>>(actB, Sbuf, dinvb);
  gemm_s<4,8><<<gs, blk, 0, stream>>>(actB, NPIX, 256, (long)MTOT-1,
                                      actB, NPIX, 256, (long)MTOT-1, ahat, dinvb);

  // GCN layer 1: t = g @ W1 (channel-major), g1 = gelu(A_hat @ t + b1)
  gemm_g<8,2><<<gg, blk, 0, stream>>>(actA, bt_gcn, tcm, nullptr, nullptr, 0,0);
  gemm_s<5,7><<<gs, blk, 0, stream>>>(ahat, NPAD, NPAD, (long)B_N*NPAD-1,
                                      tcm, 256, NPAD, (long)B_N*256-1, actB, gcn_b);
  // GCN layer 2
  gemm_g<8,2><<<gg, blk, 0, stream>>>(actB, bt_gcn + 65536, tcm, nullptr, nullptr, 0,0);
  gemm_s<5,7><<<gs, blk, 0, stream>>>(ahat, NPAD, NPAD, (long)B_N*NPAD-1,
                                      tcm, 256, NPAD, (long)B_N*256-1, actA, gcn_b + 256);

  // Upsample head convs; second one also writes fp32 feats (output 1)
  gemm_conv<0><<<gc, dim3(512), 0, stream>>>(actA, bt_up + 0L*589824, actB, nullptr, up_b + 0);
  gemm_conv<1><<<gc, dim3(512), 0, stream>>>(actB, bt_up + 1L*589824, actA, feats,   up_b + 256);

  // Fused ConvTranspose(k2,s2)+ReLU+pred(1x1) — R8-verbatim (known-good)
  k_decpred<<<dim3(MTOT/64), dim3(512), 0, stream>>>(actA, bt_dec, bt_pred,
                                                     dec_b, pred_b, mask);
}